// Round 9
// baseline (1030.692 us; speedup 1.0000x reference)
//
#include <hip/hip_runtime.h>

#define N_SAMPLES 65536
#define K_CENT    1024
#define DIM       512
// fp16 1-term screen: dist error = -2*(a.bl + al.bh), sigma ~ 9.2e-3.
// TAU = 0.125 ~ 13.6 sigma; flag-and-fp64-refine fixes all flagged near-ties.
#define TAU 0.125f

typedef __attribute__((ext_vector_type(8))) short  short8;
typedef _Float16 half8 __attribute__((ext_vector_type(8)));
typedef __attribute__((ext_vector_type(4))) float  float4v;

__device__ inline unsigned short f2h_bits(float x) {
    _Float16 h = (_Float16)x;
    return __builtin_bit_cast(unsigned short, h);
}

// ---------------- pack: Bp = fp16 centers in fragment-slot order, + c2 ----------------
// Bp slot (16B): s16 = (ntG*16+kk)*512 + j4*64 + quad*16 + l15
//   content = centers[ntG*128 + j4*16 + l15][kk*32 + quad*8 .. +8] as fp16
// so assign's per-j4 B load at global step s is Bp + s*4096 + j4*512 + lane*8 (shorts):
// perfectly coalesced, 16B/lane.
__global__ __launch_bounds__(256) void pack_kernel(const float* __restrict__ cen,
                                                   unsigned short* __restrict__ Bp,
                                                   float* __restrict__ c2) {
    const int wv = threadIdx.x >> 6, lane = threadIdx.x & 63;
    const int k = blockIdx.x * 4 + wv;          // center row 0..1023
    const int kk = lane >> 2, quad = lane & 3;  // 16 kk x 4 quad = 64 lanes
    const float* src = cen + (size_t)k * DIM + kk * 32 + quad * 8;
    float4 v0 = *(const float4*)src;
    float4 v1 = *(const float4*)(src + 4);
    float f[8] = {v0.x, v0.y, v0.z, v0.w, v1.x, v1.y, v1.z, v1.w};
    short8 h;
    float s = 0.f;
    #pragma unroll
    for (int e = 0; e < 8; ++e) { h[e] = (short)f2h_bits(f[e]); s += f[e] * f[e]; }
    const int ntG = k >> 7, j4 = (k >> 4) & 7, l15 = k & 15;
    size_t slot = (size_t)(ntG * 16 + kk) * 512 + j4 * 64 + quad * 16 + l15;
    *(short8*)(Bp + slot * 8) = h;
    for (int off = 32; off; off >>= 1) s += __shfl_down(s, off);
    if (lane == 0) c2[k] = s;
}

__device__ inline void loadA(const float* aBase, int kc, float4v av[2][2]) {
    #pragma unroll
    for (int i = 0; i < 2; ++i) {
        const float4v* ap = (const float4v*)(aBase + (size_t)i * 16 * DIM + kc);
        av[i][0] = ap[0];
        av[i][1] = ap[1];
    }
}

__device__ inline void cvtA1(const float4v av[2][2], half8 ah[2]) {
    #pragma unroll
    for (int i = 0; i < 2; ++i) {
        #pragma unroll
        for (int e = 0; e < 8; ++e)
            ah[i][e] = (_Float16)av[i][e >> 2][e & 3];
    }
}

#define LOAD_B(dst, sstep)                                                       \
    {                                                                            \
        const unsigned short* bk_ = Bp + (size_t)(sstep) * 4096;                 \
        _Pragma("unroll")                                                        \
        for (int j_ = 0; j_ < 8; ++j_)                                           \
            dst[j_] = *(const short8*)(bk_ + j_ * 512 + lane * 8);               \
    }

#define MFMA_STEP(bsrc)                                                          \
    {                                                                            \
        _Pragma("unroll")                                                        \
        for (int j4_ = 0; j4_ < 8; ++j4_) {                                      \
            half8 bh_ = __builtin_bit_cast(half8, bsrc[j4_]);                    \
            acc[j4_]     = __builtin_amdgcn_mfma_f32_16x16x32_f16(               \
                ah[0], bh_, acc[j4_], 0, 0, 0);                                  \
            acc[8 + j4_] = __builtin_amdgcn_mfma_f32_16x16x32_f16(               \
                ah[1], bh_, acc[8 + j4_], 0, 0, 0);                              \
        }                                                                        \
    }

// ---------------- MFMA assign: 128m x 1024n per block (single chunk), fp16 1-term --------
// Grid 512 blocks (2/CU, grid-limited -> VGPRs up to 256 are free: launch_bounds(256,1)).
// B: NAMED register double-buffer brA/brB, prefetched one full step ahead (no parity
// array indexing -> cannot spill via rule-#20). A: raw-prefetch + cvt-at-end.
// Merge is FUSED into the epilogue: s_idx/out_s/hist/flags/loss written directly.
__global__ __launch_bounds__(256, 1) void assign_mfma(
    const float* __restrict__ A,            // embedded [N,D] fp32
    const unsigned short* __restrict__ Bp,  // packed fp16 centers (1 MB, L2-resident)
    const float* __restrict__ c2,
    int* __restrict__ s_idx,
    float* __restrict__ out_s,
    int* __restrict__ hist,
    int* __restrict__ flag_cnt,
    int* __restrict__ flagged,
    double* __restrict__ loss_d)
{
    __shared__ float st_best[128];
    __shared__ float st_sec[128];
    __shared__ int   st_idx[128];

    const int tid  = threadIdx.x;
    const int w    = tid >> 6;        // wave 0..3: rows w*32..w*32+31
    const int lane = tid & 63;
    const int quad = lane >> 4;
    const int l15  = lane & 15;
    const int m0   = blockIdx.x * 128;

    if (tid < 128) { st_best[tid] = 3.4e38f; st_sec[tid] = 3.4e38f; st_idx[tid] = 0; }
    __syncthreads();   // init visible before any wave's epilogue updates

    // per-lane A base: row = m0 + w*32 + l15 (+ i*16), col = quad*8 (+ step*32)
    const float* aBase = A + (size_t)(m0 + w * 32 + l15) * DIM + quad * 8;

    short8 brA[8], brB[8];   // named double buffer (no dynamic indexing)
    float4v avN[2][2];
    half8 ah[2];

    // prologue: B(0) -> brA, A(0) -> ah
    LOAD_B(brA, 0);
    loadA(aBase, 0, avN);
    cvtA1(avN, ah);

    for (int nt = 0; nt < 8; ++nt) {
        const int n0 = nt * 128;
        const int sBase = nt * 16;

        float4v acc[16];
        #pragma unroll
        for (int z = 0; z < 16; ++z) acc[z] = (float4v){0.f, 0.f, 0.f, 0.f};

        #pragma unroll
        for (int ks2 = 0; ks2 < 8; ++ks2) {
            const int s = sBase + ks2 * 2;
            // ---- half 0: prefetch step s+1 -> brB; compute on brA (step s) ----
            LOAD_B(brB, s + 1);
            loadA(aBase, ((s + 1) & 15) * 32, avN);
            MFMA_STEP(brA);
            cvtA1(avN, ah);                       // ah := A(s+1), loads drained under MFMAs
            // ---- half 1: prefetch step s+2 -> brA; compute on brB (step s+1) ----
            {
                const int s2 = (s + 2 < 128) ? s + 2 : 127;   // uniform clamp (dummy at end)
                LOAD_B(brA, s2);
            }
            loadA(aBase, ((s + 2) & 15) * 32, avN);
            MFMA_STEP(brB);
            cvtA1(avN, ah);                       // ah := A(s+2)
        }
        // here brA = B((nt+1)*16), ah = A col 0 of next nt: ready for next pass

        // epilogue: dist = c2[n] - 2*cross; per-lane best over j, butterfly over l15
        float c2v[8];
        #pragma unroll
        for (int j = 0; j < 8; ++j) c2v[j] = c2[n0 + j * 16 + l15];
        #pragma unroll
        for (int i = 0; i < 2; ++i)
            #pragma unroll
            for (int reg = 0; reg < 4; ++reg) {
                float bv = 3.4e38f, sv = 3.4e38f; int bi = 0;
                #pragma unroll
                for (int j = 0; j < 8; ++j) {
                    float v = c2v[j] - 2.0f * acc[i * 8 + j][reg];
                    int n = n0 + j * 16 + l15;
                    if (v < bv) { sv = bv; bv = v; bi = n; }
                    else if (v < sv) sv = v;
                }
                #pragma unroll
                for (int mask = 1; mask < 16; mask <<= 1) {
                    float ob = __shfl_xor(bv, mask);
                    float os = __shfl_xor(sv, mask);
                    int   oi = __shfl_xor(bi, mask);
                    float ns = fminf(fminf(sv, os), fmaxf(bv, ob));
                    if (ob < bv || (ob == bv && oi < bi)) { bv = ob; bi = oi; }
                    sv = ns;
                }
                if (l15 == 0) {   // unique writer per m (rows wave-exclusive, no race)
                    int ml = w * 32 + i * 16 + quad * 4 + reg;
                    float sb = st_best[ml], ss = st_sec[ml]; int si = st_idx[ml];
                    float ns = fminf(fminf(ss, sv), fmaxf(sb, bv));
                    if (bv < sb || (bv == sb && bi < si)) { st_best[ml] = bv; st_idx[ml] = bi; }
                    st_sec[ml] = ns;
                }
            }
    }

    __syncthreads();   // st_* complete
    // fused merge: outputs, histogram, tie flags, loss partial
    if (tid < 128) {
        int m = m0 + tid;
        float bv = st_best[tid], sv = st_sec[tid];
        int   bi = st_idx[tid];
        s_idx[m] = bi;
        out_s[m] = (float)bi;
        atomicAdd(&hist[bi], 1);
        if (sv - bv < TAU) { int p = atomicAdd(flag_cnt, 1); flagged[p] = m; }
        float ls = bv;
        #pragma unroll
        for (int off = 32; off; off >>= 1) ls += __shfl_down(ls, off);
        if (lane == 0) atomicAdd(loss_d, (double)ls);   // waves 0,1: 2 atomics/block
    }
}

// ---------------- exact fp64 re-check of flagged near-tie samples (+hist fixup) ----------------
__global__ __launch_bounds__(256) void refine_kernel(
    const float* __restrict__ emb,
    const float* __restrict__ cen,
    const int* __restrict__ flag_cnt,
    const int* __restrict__ flagged,
    int* __restrict__ s_idx,
    float* __restrict__ out_s,
    int* __restrict__ hist)
{
    __shared__ float e_sh[DIM];
    __shared__ double rvd[256];
    __shared__ int rid[256];
    const int t = threadIdx.x;
    const int cnt = *flag_cnt;
    for (int idx = blockIdx.x; idx < cnt; idx += gridDim.x) {
        int n = flagged[idx];
        __syncthreads();
        ((float2*)e_sh)[t] = ((const float2*)(emb + (size_t)n * DIM))[t];
        __syncthreads();
        double bestd = 1e300;
        int bestk = 0;
        #pragma unroll
        for (int j = 0; j < 4; ++j) {
            int k = t * 4 + j;
            const float* crow = cen + (size_t)k * DIM;
            double acc = 0.0;
            for (int d = 0; d < DIM; d += 4) {
                float4 cv = *(const float4*)(crow + d);
                double d0 = (double)e_sh[d + 0] - (double)cv.x;
                double d1 = (double)e_sh[d + 1] - (double)cv.y;
                double d2 = (double)e_sh[d + 2] - (double)cv.z;
                double d3 = (double)e_sh[d + 3] - (double)cv.w;
                acc += d0 * d0 + d1 * d1 + d2 * d2 + d3 * d3;
            }
            if (acc < bestd) { bestd = acc; bestk = k; }
        }
        rvd[t] = bestd; rid[t] = bestk;
        __syncthreads();
        for (int off = 128; off; off >>= 1) {
            if (t < off) {
                double v = rvd[t + off]; int ii = rid[t + off];
                if (v < rvd[t] || (v == rvd[t] && ii < rid[t])) { rvd[t] = v; rid[t] = ii; }
            }
            __syncthreads();
        }
        if (t == 0) {
            int old = s_idx[n], nw = rid[0];
            if (nw != old) {
                atomicSub(&hist[old], 1);
                atomicAdd(&hist[nw], 1);
                s_idx[n] = nw;
                out_s[n] = (float)nw;
            }
        }
    }
}

// ---------------- prefix sum over histogram ----------------
__global__ void scan_kernel(const int* __restrict__ hist,
                            int* __restrict__ offsets,
                            int* __restrict__ cursor,
                            const int* __restrict__ count_in,
                            float* __restrict__ out_count) {
    __shared__ int sbuf[K_CENT];
    int t = threadIdx.x;
    int v = hist[t];
    sbuf[t] = v;
    __syncthreads();
    for (int off = 1; off < K_CENT; off <<= 1) {
        int x = (t >= off) ? sbuf[t - off] : 0;
        __syncthreads();
        sbuf[t] += x;
        __syncthreads();
    }
    int incl = sbuf[t];
    offsets[t] = incl - v;
    cursor[t]  = incl - v;
    out_count[t] = (float)(count_in[t] + v);
    if (t == K_CENT - 1) offsets[K_CENT] = incl;
}

__global__ void scatter_kernel(const int* __restrict__ s_idx,
                               int* __restrict__ cursor,
                               int* __restrict__ order) {
    int n = blockIdx.x * blockDim.x + threadIdx.x;
    if (n < N_SAMPLES) {
        int pos = atomicAdd(&cursor[s_idx[n]], 1);
        order[pos] = n;
    }
}

// ---------------- balanced partial segment sums (fixed 64-entry slices) ----------------
__global__ __launch_bounds__(256) void gp_kernel(
    const float* __restrict__ emb,
    const int* __restrict__ s_idx,
    const int* __restrict__ order,
    float* __restrict__ accum,
    double* __restrict__ loss_d)
{
    __shared__ int s_n[64], s_c[64];
    const int t = threadIdx.x;
    const int base = blockIdx.x * 64;
    if (t < 64) { int n = order[base + t]; s_n[t] = n; s_c[t] = s_idx[n]; }
    __syncthreads();
    float ax = 0.f, ay = 0.f, ssq = 0.f;
    int cur = s_c[0];
    for (int r = 0; r < 64; ++r) {
        int n = s_n[r], c = s_c[r];
        if (c != cur) {   // uniform branch (shared value)
            atomicAdd(&accum[(size_t)cur * DIM + t * 2], ax);
            atomicAdd(&accum[(size_t)cur * DIM + t * 2 + 1], ay);
            ax = ay = 0.f; cur = c;
        }
        float2 e = *(const float2*)(emb + (size_t)n * DIM + t * 2);
        ax += e.x; ay += e.y;
        ssq += e.x * e.x + e.y * e.y;
    }
    atomicAdd(&accum[(size_t)cur * DIM + t * 2], ax);
    atomicAdd(&accum[(size_t)cur * DIM + t * 2 + 1], ay);

    for (int off = 32; off; off >>= 1) ssq += __shfl_down(ssq, off);
    __shared__ float wsum[4];
    if ((t & 63) == 0) wsum[t >> 6] = ssq;
    __syncthreads();
    if (t == 0)
        atomicAdd(loss_d, (double)(wsum[0] + wsum[1] + wsum[2] + wsum[3]));
}

// ---------------- combine: out_centers = (cnt*c + accum) / (cnt + hist); finalize loss ----------------
__global__ __launch_bounds__(256) void combine_kernel(
    const float* __restrict__ centers,
    const int* __restrict__ count_in,
    const int* __restrict__ hist,
    const float* __restrict__ accum,
    const double* __restrict__ loss_d,
    float* __restrict__ out_centers,
    float* __restrict__ out_loss)
{
    int k = blockIdx.x, t = threadIdx.x;
    if (k == 0 && t == 0) *out_loss = (float)(*loss_d * (1.0 / N_SAMPLES));
    float cn = (float)count_in[k];
    float tot = cn + (float)hist[k];
    float2 c = *(const float2*)(centers + (size_t)k * DIM + t * 2);
    float2 a = *(const float2*)(accum   + (size_t)k * DIM + t * 2);
    float2 o;
    o.x = (cn * c.x + a.x) / tot;
    o.y = (cn * c.y + a.y) / tot;
    *(float2*)(out_centers + (size_t)k * DIM + t * 2) = o;
}

extern "C" void kernel_launch(void* const* d_in, const int* in_sizes, int n_in,
                              void* d_out, int out_size, void* d_ws, size_t ws_size,
                              hipStream_t stream) {
    const float* emb = (const float*)d_in[0];
    const float* cen = (const float*)d_in[1];
    const int*   cnt = (const int*)d_in[2];

    float* out = (float*)d_out;
    float* out_loss    = out;
    float* out_s       = out + 1;
    float* out_centers = out + 1 + N_SAMPLES;
    float* out_count   = out + 1 + N_SAMPLES + (size_t)K_CENT * DIM;

    int* wsi = (int*)d_ws;
    int*   hist     = wsi;                       // [0, 1024)
    int*   offsets  = wsi + 1024;                // [1024, 2049) +pad
    int*   cursor   = wsi + 2064;                // [2064, 3088)
    int*   s_idx    = wsi + 4096;                // [4096, 69632)
    float* c2       = (float*)(wsi + 69632);     // [69632, 70656)
    int*   flag_cnt = wsi + 70656;               // 1 int, padded region [70656, 70712)
    double* loss_d  = (double*)(wsi + 70712);    // [70712, 70714) 8B-aligned, no overlap
    int*   flagged  = wsi + 70720;               // [70720, 136256)
    int*   order    = wsi + 136256;              // [136256, 201792)
    unsigned short* Bp = (unsigned short*)(wsi + 529472);  // [529472, 791616) packed fp16
    // alias (lifetimes disjoint):
    float* accum    = (float*)(wsi + 529472);    // aliases Bp+ (dead after assign)

    hipMemsetAsync(hist, 0, K_CENT * sizeof(int), stream);
    hipMemsetAsync(loss_d, 0, sizeof(double), stream);
    hipMemsetAsync(flag_cnt, 0, sizeof(int), stream);

    pack_kernel<<<256, 256, 0, stream>>>(cen, Bp, c2);
    assign_mfma<<<512, 256, 0, stream>>>(emb, Bp, c2, s_idx, out_s,
                                         hist, flag_cnt, flagged, loss_d);
    // Bp dead; reuse region as accumulation buffer
    hipMemsetAsync(accum, 0, (size_t)K_CENT * DIM * sizeof(float), stream);
    refine_kernel<<<256, 256, 0, stream>>>(emb, cen, flag_cnt, flagged, s_idx, out_s, hist);
    scan_kernel<<<1, K_CENT, 0, stream>>>(hist, offsets, cursor, cnt, out_count);
    scatter_kernel<<<N_SAMPLES / 256, 256, 0, stream>>>(s_idx, cursor, order);
    gp_kernel<<<N_SAMPLES / 64, 256, 0, stream>>>(emb, s_idx, order, accum, loss_d);
    combine_kernel<<<K_CENT, 256, 0, stream>>>(cen, cnt, hist, accum, loss_d,
                                               out_centers, out_loss);
}